// Round 2
// baseline (89.446 us; speedup 1.0000x reference)
//
#include <hip/hip_runtime.h>

// L1 pairwise distance: out[i][j] = sum_d |x1[i][d] - x2[j][d]|
// x1: [2048, 64] f32, x2: [2048, 64] f32, out: [2048, 2048] f32.
// Mean-adjustment in the reference cancels: (x1-adj)-(x2-adj) = x1-x2.
// clamp_min(0) is a no-op on a sum of |.|.
//
// R6 = R5 with the harness-semantics fix: in_sizes[] is in ELEMENTS (R4
// divided by D_FIXED only). R5 divided by D_FIXED*sizeof(float) -> n=512 ->
// 128 blocks -> 15/16 of output never written -> absmax 109. Kernel body
// unchanged.
//
// Structure (R5 theory): LDS-free register/SGPR formulation. R4's pipe
// arithmetic: VALU floor 16.4K cyc/CU (6.8us) but LDS ds_read_b128
// throughput 18.4K cyc/CU (7.7us, m134: 12cyc/instr) -> LDS was the
// binding pipe, plus a barrier. New structure: 1 wave per block, lane =
// output column.
//   - b = x2 row (j0+lane): 64 floats resident in 64 VGPRs (16 float4),
//     loaded once per block (16KB from L2; x2 is only 512KB -> L2-hot).
//   - a = x1 row: address depends only on blockIdx.y + loop counter ->
//     wave-uniform -> s_load into SGPRs; v_sub_f32 takes the SGPR as src0,
//     abs folds into v_add_f32 input modifier. 2 VALU per element-op = floor.
//   - zero LDS, zero barriers. 2048 blocks = 8 waves/CU = 2/SIMD; the other
//     wave's 256-cyc row-compute hides this wave's ~200-cyc s_load wait.
// Predicted kernel ~7.5us (VALU-bound) vs R4 ~10us; total 69.9 -> ~67.5us.

#define D_FIXED 64
#define ROWS 32   // x1 rows per block
#define JT   64   // x2 columns per block = wavefront size

__global__ __launch_bounds__(64, 2)
void l1dist_kernel(const float* __restrict__ x1, const float* __restrict__ x2,
                   float* __restrict__ out, int N1, int N2) {
    const int lane = threadIdx.x;            // 0..63 -> output column j0+lane
    const int j0 = blockIdx.x * JT;
    const int i0 = blockIdx.y * ROWS;

    // ---- x2 row (j0+lane) resident in VGPRs: 16 float4 = 64 VGPRs ----
    // Strided across lanes (256B/lane) but tiny: 16KB/block, L2-served.
    const float4* xb = (const float4*)(x2 + (size_t)(j0 + lane) * D_FIXED);
    float4 b[16];
    #pragma unroll
    for (int q = 0; q < 16; ++q) b[q] = xb[q];

    const float* a = x1 + (size_t)i0 * D_FIXED;   // wave-uniform address
    float* o = out + (size_t)i0 * N2 + (j0 + lane);

    #pragma unroll 2
    for (int r = 0; r < ROWS; ++r) {
        // 4 partial accumulators: dependency chains of 16 adds (64cy) per
        // row vs 256 issue cycles -> latency never binds.
        float p0 = 0.f, p1 = 0.f, p2 = 0.f, p3 = 0.f;
        #pragma unroll
        for (int q = 0; q < 16; ++q) {
            const float4 bb = b[q];
            const float a0 = a[4 * q + 0];   // s_load_dwordx16 cluster
            const float a1 = a[4 * q + 1];
            const float a2 = a[4 * q + 2];
            const float a3 = a[4 * q + 3];
            p0 += fabsf(a0 - bb.x);          // v_sub_f32 v,s,v ; v_add |.|
            p1 += fabsf(a1 - bb.y);
            p2 += fabsf(a2 - bb.z);
            p3 += fabsf(a3 - bb.w);
        }
        // write-once output -> nontemporal; 256B contiguous per wave-store
        __builtin_nontemporal_store((p0 + p1) + (p2 + p3), o);
        a += D_FIXED;
        o += N2;
    }
}

extern "C" void kernel_launch(void* const* d_in, const int* in_sizes, int n_in,
                              void* d_out, int out_size, void* d_ws, size_t ws_size,
                              hipStream_t stream) {
    const float* x1 = (const float*)d_in[0];
    const float* x2 = (const float*)d_in[1];
    float* out = (float*)d_out;

    // in_sizes[] is ELEMENT count (R4-verified): 2048*64 = 131072.
    const int n1 = in_sizes[0] / D_FIXED;  // 2048
    const int n2 = in_sizes[1] / D_FIXED;  // 2048

    dim3 block(JT);
    dim3 grid(n2 / JT, n1 / ROWS);   // (32, 64) = 2048 blocks = 8 waves/CU
    l1dist_kernel<<<grid, block, 0, stream>>>(x1, x2, out, n1, n2);
}

// Round 3
// 82.375 us; speedup vs baseline: 1.0858x; 1.0858x over previous
//
#include <hip/hip_runtime.h>

// L1 pairwise distance: out[i][j] = sum_d |x1[i][d] - x2[j][d]|
// x1: [2048, 64] f32, x2: [2048, 64] f32, out: [2048, 2048] f32.
// Mean-adjustment cancels; clamp_min(0) is a no-op on a sum of |.|.
//
// R7: back to the R4 structure (LDS one-shot staging, ONE barrier, 2D
// register tile) after R6's register/SGPR formulation regressed (30us
// kernel: compiler can't promote loop-carried global loads to s_load ->
// 512 VMEM/wave at 200cyc L2 latency, 2 waves/SIMD can't hide it).
// Deltas vs R4 (measured 69.9us total, ~10us kernel, VALU-bound ~16.4K
// cyc/CU at 2 VALU/elem):
//  1. Packed-f32 subtract: v_pk_add_f32 (gfx90a+ full-rate, neg modifier)
//     via ext_vector float2 -> 2 pk-subs + 4 abs-adds per 4 elems
//     = 1.5 VALU/elem -> VALU floor 12.3K cyc/CU (5.1us).
//  2. 8x8 per-thread tile (was 8x4): LDS instr/elem halves (16 reads per
//     64 outs vs 12 per 32) in case LDS was co-binding. 128-thr blocks,
//     512 blocks = 2 blocks/CU (4 waves/CU): block A's compute covers
//     block B's staging; 64 independent accs give the ILP for 1 wave/SIMD.
// Bank math: PAD=68 -> row stride 4 banks; 8 distinct rows/read span all
// 32 banks exactly once (broadcast x8 free) -> conflict-free.

#define D_FIXED 64
#define BI 128   // x1 rows per block
#define BJ 64    // x2 cols per block
#define PAD 68   // 16B-aligned rows; 4-bank shift/row

typedef float v2f __attribute__((ext_vector_type(2)));

__global__ __launch_bounds__(128, 1)
void l1dist_kernel(const float* __restrict__ x1, const float* __restrict__ x2,
                   float* __restrict__ out, int N1, int N2) {
    __shared__ float s1[BI * PAD];  // 34816 B
    __shared__ float s2[BJ * PAD];  // 17408 B (52.2KB total, 3 blocks/CU by LDS)

    const int tx = threadIdx.x;     // 0..7  -> output col j = j0 + tx + 8c
    const int ty = threadIdx.y;     // 0..15 -> output row i = i0 + ty + 16r
    const int t  = ty * 8 + tx;     // 0..127
    const int i0 = blockIdx.y * BI;
    const int j0 = blockIdx.x * BJ;

    // ---- one-shot staging (coalesced float4), same pattern as R4 ----
    const float* g1 = x1 + (size_t)i0 * D_FIXED;
    #pragma unroll
    for (int f = 0; f < 16; ++f) {          // 2048 float4s / 128 threads
        int idx = t + f * 128;
        int row = idx >> 4;
        int c4  = (idx & 15) << 2;
        *(float4*)(s1 + row * PAD + c4) = *(const float4*)(g1 + row * D_FIXED + c4);
    }
    const float* g2 = x2 + (size_t)j0 * D_FIXED;
    #pragma unroll
    for (int f = 0; f < 8; ++f) {           // 1024 float4s / 128 threads
        int idx = t + f * 128;
        int row = idx >> 4;
        int c4  = (idx & 15) << 2;
        *(float4*)(s2 + row * PAD + c4) = *(const float4*)(g2 + row * D_FIXED + c4);
    }
    __syncthreads();                         // the ONLY barrier

    // ---- 8x8 register tile ----
    float acc[8][8];
    #pragma unroll
    for (int r = 0; r < 8; ++r)
        #pragma unroll
        for (int c = 0; c < 8; ++c) acc[r][c] = 0.0f;

    #pragma unroll
    for (int d = 0; d < D_FIXED; d += 4) {   // FULL unroll (R3: bounding regressed)
        float4 a[8], b[8];
        #pragma unroll
        for (int c = 0; c < 8; ++c)          // 8 distinct rows -> 32 banks once
            b[c] = *(const float4*)(s2 + (tx + 8 * c) * PAD + d);
        #pragma unroll
        for (int r = 0; r < 8; ++r)          // broadcast across tx
            a[r] = *(const float4*)(s1 + (ty + 16 * r) * PAD + d);

        #pragma unroll
        for (int r = 0; r < 8; ++r) {
            const v2f alo = {a[r].x, a[r].y};
            const v2f ahi = {a[r].z, a[r].w};
            #pragma unroll
            for (int c = 0; c < 8; ++c) {
                const v2f blo = {b[c].x, b[c].y};
                const v2f bhi = {b[c].z, b[c].w};
                const v2f dlo = alo - blo;   // v_pk_add_f32 (neg) : 2 elems/instr
                const v2f dhi = ahi - bhi;
                // abs folds into v_add_f32 input modifiers: 4 instrs / 4 elems
                acc[r][c] += (fabsf(dlo.x) + fabsf(dlo.y)) +
                             (fabsf(dhi.x) + fabsf(dhi.y));
            }
        }
    }

    // ---- store: write-once -> nontemporal; 32B contiguous per instr ----
    #pragma unroll
    for (int r = 0; r < 8; ++r) {
        const size_t i = i0 + ty + 16 * r;
        #pragma unroll
        for (int c = 0; c < 8; ++c) {
            const int j = j0 + tx + 8 * c;
            __builtin_nontemporal_store(acc[r][c], &out[i * N2 + j]);
        }
    }
}

extern "C" void kernel_launch(void* const* d_in, const int* in_sizes, int n_in,
                              void* d_out, int out_size, void* d_ws, size_t ws_size,
                              hipStream_t stream) {
    const float* x1 = (const float*)d_in[0];
    const float* x2 = (const float*)d_in[1];
    float* out = (float*)d_out;

    // in_sizes[] is ELEMENT count (R4/R6-verified): 2048*64 = 131072.
    const int N1 = in_sizes[0] / D_FIXED;  // 2048
    const int N2 = in_sizes[1] / D_FIXED;  // 2048

    dim3 block(8, 16);
    dim3 grid(N2 / BJ, N1 / BI);           // (32, 16) = 512 blocks = 2/CU
    l1dist_kernel<<<grid, block, 0, stream>>>(x1, x2, out, N1, N2);
}

// Round 4
// 71.946 us; speedup vs baseline: 1.2432x; 1.1450x over previous
//
#include <hip/hip_runtime.h>

// L1 pairwise distance: out[i][j] = sum_d |x1[i][d] - x2[j][d]|
// x1: [2048, 64] f32, x2: [2048, 64] f32, out: [2048, 2048] f32.
// Mean-adjustment cancels; clamp_min(0) is a no-op on a sum of |.|.
//
// R8 = R4 (best measured, 69.9us) + ONE change: packed-f32 subtract.
// R7's double-change (pk + 8x8/128thr) regressed to ~22us kernel -- suspect
// spills/1-wave-per-SIMD latency exposure; reverted wholesale.
// Pipe model for R4: VALU 16.4K cyc/CU (6.8us, 2 instr/elem), LDS 18.4K
// cyc/CU (7.7us, 1536 ds_read_b128 x 12cyc). pk-sub cuts VALU to 12.3K
// (5.1us): per 4 elems = 2 v_pk_add_f32(neg) + 4 v_add_f32(abs mods)
// = 1.5 instr/elem. ds_read_b128 dest is 4-aligned so .xy/.zw are even
// VGPR pairs -> pk ops need no marshaling movs.
// Predict: kernel ~8.5-9us (LDS now binding), total 69.9 -> ~68.5.
// If neutral -> LDS-bound confirmed -> next round cuts LDS instr/elem.

#define D_FIXED 64
#define BI 128   // x1 rows per block
#define BJ 64    // x2 cols per block
#define PAD 68   // rows 16B-aligned; bank shift 4/row -> <=2-way alias (free, m136)

typedef float v2f __attribute__((ext_vector_type(2)));

__global__ __launch_bounds__(256, 2)
void l1dist_kernel(const float* __restrict__ x1, const float* __restrict__ x2,
                   float* __restrict__ out, int N1, int N2) {
    __shared__ float s1[BI * PAD];  // 34816 B
    __shared__ float s2[BJ * PAD];  // 17408 B  (51KB total)

    const int tx = threadIdx.x;     // 0..15
    const int ty = threadIdx.y;     // 0..15
    const int t  = ty * 16 + tx;
    const int i0 = blockIdx.y * BI;
    const int j0 = blockIdx.x * BJ;

    // ---- one-shot staging (coalesced float4) ----
    const float* g1 = x1 + (size_t)i0 * D_FIXED;
    #pragma unroll
    for (int f = 0; f < 8; ++f) {           // 2048 float4s / 256 threads
        int idx = t + f * 256;
        int row = idx >> 4;
        int c4  = (idx & 15) << 2;
        *(float4*)(s1 + row * PAD + c4) = *(const float4*)(g1 + row * D_FIXED + c4);
    }
    const float* g2 = x2 + (size_t)j0 * D_FIXED;
    #pragma unroll
    for (int f = 0; f < 4; ++f) {           // 1024 float4s / 256 threads
        int idx = t + f * 256;
        int row = idx >> 4;
        int c4  = (idx & 15) << 2;
        *(float4*)(s2 + row * PAD + c4) = *(const float4*)(g2 + row * D_FIXED + c4);
    }
    __syncthreads();                         // the ONLY barrier

    // ---- 8x4 register tile: rows i = ty+16r, cols j = tx+16c ----
    float acc[8][4];
    #pragma unroll
    for (int r = 0; r < 8; ++r)
        #pragma unroll
        for (int c = 0; c < 4; ++c) acc[r][c] = 0.0f;

    #pragma unroll
    for (int d = 0; d < D_FIXED; d += 4) {   // FULL unroll (R3's bound regressed)
        float4 a[8], b[4];
        #pragma unroll
        for (int c = 0; c < 4; ++c)          // <=2-way bank alias (free)
            b[c] = *(const float4*)(s2 + (tx + 16 * c) * PAD + d);
        #pragma unroll
        for (int r = 0; r < 8; ++r)          // wave-broadcast (4 addrs/wave)
            a[r] = *(const float4*)(s1 + (ty + 16 * r) * PAD + d);

        #pragma unroll
        for (int r = 0; r < 8; ++r) {
            const v2f alo = {a[r].x, a[r].y};
            const v2f ahi = {a[r].z, a[r].w};
            #pragma unroll
            for (int c = 0; c < 4; ++c) {
                const v2f blo = {b[c].x, b[c].y};
                const v2f bhi = {b[c].z, b[c].w};
                const v2f dlo = alo - blo;   // v_pk_add_f32 (neg mod): 2 elems/instr
                const v2f dhi = ahi - bhi;
                // abs folds into v_add_f32 input modifiers: 4 adds / 4 elems
                acc[r][c] += (fabsf(dlo.x) + fabsf(dlo.y)) +
                             (fabsf(dhi.x) + fabsf(dhi.y));
            }
        }
    }

    // ---- store: write-once output -> nontemporal; 64B segments per line ----
    #pragma unroll
    for (int r = 0; r < 8; ++r) {
        const size_t i = i0 + ty + 16 * r;
        #pragma unroll
        for (int c = 0; c < 4; ++c) {
            const int j = j0 + tx + 16 * c;
            __builtin_nontemporal_store(acc[r][c], &out[i * N2 + j]);
        }
    }
}

extern "C" void kernel_launch(void* const* d_in, const int* in_sizes, int n_in,
                              void* d_out, int out_size, void* d_ws, size_t ws_size,
                              hipStream_t stream) {
    const float* x1 = (const float*)d_in[0];
    const float* x2 = (const float*)d_in[1];
    float* out = (float*)d_out;

    // in_sizes[] is ELEMENT count (R4/R6-verified): 2048*64 = 131072.
    const int N1 = in_sizes[0] / D_FIXED;  // 2048
    const int N2 = in_sizes[1] / D_FIXED;  // 2048

    dim3 block(16, 16);
    dim3 grid(N2 / BJ, N1 / BI);           // (32, 16) = 512 blocks = 2/CU
    l1dist_kernel<<<grid, block, 0, stream>>>(x1, x2, out, N1, N2);
}